// Round 11
// baseline (205.284 us; speedup 1.0000x reference)
//
#include <hip/hip_runtime.h>
#include <hip/hip_bf16.h>

#define DIM   768
#define NH    12
#define HD    64
#define BB    2
#define SS    2048
#define QKVN  (3 * DIM)   // 2304
#define MM    (BB * SS)   // 4096

typedef __attribute__((ext_vector_type(8))) short bf16x8;
typedef __attribute__((ext_vector_type(8))) short short8;
typedef __attribute__((ext_vector_type(4))) float f32x4;

__device__ __forceinline__ short f2bf(float f) {
    unsigned int u = __float_as_uint(f);
    unsigned int r = (u + 0x7FFFu + ((u >> 16) & 1u)) >> 16;
    return (short)r;
}
__device__ __forceinline__ float bf2f(short s) {
    return __uint_as_float((unsigned int)(unsigned short)s << 16);
}

__device__ __forceinline__ void gld16(const short* g, short* l) {
    __builtin_amdgcn_global_load_lds(
        (const __attribute__((address_space(1))) void*)g,
        (__attribute__((address_space(3))) void*)l, 16, 0, 0);
}

template<int N> __device__ __forceinline__ void waitvm() {
    if constexpr (N == 0) asm volatile("s_waitcnt vmcnt(0)" ::: "memory");
    else if constexpr (N == 3) asm volatile("s_waitcnt vmcnt(3)" ::: "memory");
    else if constexpr (N == 4) asm volatile("s_waitcnt vmcnt(4)" ::: "memory");
}

// fp32 -> bf16 conversion for x, w_qkv, w_out
__global__ __launch_bounds__(256) void conv_kernel(
    const float* __restrict__ x,  short* __restrict__ xb,
    const float* __restrict__ wq, short* __restrict__ wqb,
    const float* __restrict__ wo, short* __restrict__ wob)
{
    const int nx = (MM * DIM) / 8;
    const int nq = (QKVN * DIM) / 8;
    int i8 = blockIdx.x * 256 + threadIdx.x;
    const float* src; short* dst;
    if (i8 < nx)           { src = x;  dst = xb; }
    else if (i8 < nx + nq) { i8 -= nx; src = wq; dst = wqb; }
    else                   { i8 -= nx + nq; src = wo; dst = wob; }
    const float4* p = (const float4*)src + (size_t)i8 * 2;
    float4 a = p[0], b = p[1];
    short8 r;
    r[0] = f2bf(a.x); r[1] = f2bf(a.y); r[2] = f2bf(a.z); r[3] = f2bf(a.w);
    r[4] = f2bf(b.x); r[5] = f2bf(b.y); r[6] = f2bf(b.z); r[7] = f2bf(b.w);
    *((short8*)dst + i8) = r;
}

// ------------- GEMM core: counted-vmcnt 2-buffer pipeline (unchanged R8) -----

template<int RT>
__device__ __forceinline__ void stage_op(const short* gb, int K, int k0, short* ld)
{
#pragma unroll
    for (int ii = 0; ii < RT / 64; ++ii)
        gld16(gb + (size_t)(64 * ii) * K + k0, ld + ii * 4096);
}

template<int MF, int NF>
__device__ __forceinline__ void read_frags(
    const short* lsA, const short* lsB, int arow, int brow, int kg, int sw,
    bf16x8 af[2][MF], bf16x8 bfr[2][NF])
{
#pragma unroll
    for (int kk = 0; kk < 2; ++kk) {
        const int ko = (kk * 32 + kg * 8) ^ sw;
#pragma unroll
        for (int i = 0; i < MF; ++i)
            af[kk][i] = *(const bf16x8*)&lsA[(arow + i * 16) * 64 + ko];
#pragma unroll
        for (int j = 0; j < NF; ++j)
            bfr[kk][j] = *(const bf16x8*)&lsB[(brow + j * 16) * 64 + ko];
    }
}

template<int MF, int NF>
__device__ __forceinline__ void mfma_frags(
    bf16x8 af[2][MF], bf16x8 bfr[2][NF], f32x4 acc[MF][NF])
{
#pragma unroll
    for (int kk = 0; kk < 2; ++kk)
#pragma unroll
        for (int i = 0; i < MF; ++i)
#pragma unroll
            for (int j = 0; j < NF; ++j)
                acc[i][j] = __builtin_amdgcn_mfma_f32_16x16x32_bf16(
                    af[kk][i], bfr[kk][j], acc[i][j], 0, 0, 0);
}

template<int MF, int NF, int ART, int BRT, int VC>
__device__ __forceinline__ void phase_steady(
    const short* lsA, const short* lsB, short* ldA, short* ldB,
    const short* Ab, const short* Bb, int K, int knext,
    int arow, int brow, int kg, int sw, f32x4 acc[MF][NF])
{
    bf16x8 af[2][MF], bfr[2][NF];
    read_frags<MF, NF>(lsA, lsB, arow, brow, kg, sw, af, bfr);
    asm volatile("s_waitcnt lgkmcnt(0)" ::: "memory");
    __builtin_amdgcn_s_barrier();
    stage_op<ART>(Ab, K, knext, ldA);
    stage_op<BRT>(Bb, K, knext, ldB);
    mfma_frags<MF, NF>(af, bfr, acc);
    waitvm<VC>();
    __builtin_amdgcn_s_barrier();
}

// GEMM1: BM=128, BN=128, 512 thr (8 waves 2x4), MF=4, NF=2. K=768 (NT=12).
// MEASUREMENT (R11): launched with gridDim.z=4; z is IGNORED -> 4 identical
// passes (identical bytes stored) in one dispatch so it rises above the
// harness fill kernels in the rocprof top-5. Per-copy time = dur/4.
__global__ __launch_bounds__(512) void gemm_qkv_kernel(
    const short* __restrict__ A, const short* __restrict__ Bm,
    const float* __restrict__ bias, short* __restrict__ qkvh)
{
    constexpr int K = DIM, NT = 12;
    __shared__ short lsA0[8192], lsB0[8192], lsA1[8192], lsB1[8192];

    const int t    = threadIdx.x;
    const int lane = t & 63;
    const int wid  = t >> 6;
    const int wrow = wid >> 2, wcol = wid & 3;
    const int l16  = lane & 15;
    const int kg   = lane >> 4;
    const int row0 = blockIdx.y * 128;
    const int col0 = blockIdx.x * 128;

    const int srow = t >> 3;
    const int scol = ((t & 7) ^ (srow & 7)) * 8;
    const short* Ab = A  + (size_t)(row0 + srow) * K + scol;
    const short* Bb = Bm + (size_t)(col0 + srow) * K + scol;
    short* ldA0 = lsA0 + t * 8;  short* ldB0 = lsB0 + t * 8;
    short* ldA1 = lsA1 + t * 8;  short* ldB1 = lsB1 + t * 8;
    const int arow = wrow * 64 + l16;
    const int brow = wcol * 32 + l16;
    const int sw   = (l16 & 7) * 8;

    f32x4 acc[4][2];
#pragma unroll
    for (int i = 0; i < 4; ++i)
#pragma unroll
        for (int j = 0; j < 2; ++j) acc[i][j] = (f32x4){0.f, 0.f, 0.f, 0.f};

    stage_op<128>(Ab, K, 0, ldA0);
    stage_op<128>(Bb, K, 0, ldB0);
    stage_op<128>(Ab, K, 64, ldA1);
    stage_op<128>(Bb, K, 64, ldB1);
    waitvm<4>();
    __builtin_amdgcn_s_barrier();

#pragma unroll
    for (int kt = 0; kt < NT - 2; kt += 2) {
        phase_steady<4, 2, 128, 128, 4>(lsA0, lsB0, ldA0, ldB0, Ab, Bb, K,
                                        (kt + 2) * 64, arow, brow, kg, sw, acc);
        phase_steady<4, 2, 128, 128, 4>(lsA1, lsB1, ldA1, ldB1, Ab, Bb, K,
                                        (kt + 3) * 64, arow, brow, kg, sw, acc);
    }
    {
        bf16x8 af[2][4], bfr[2][2];
        read_frags<4, 2>(lsA0, lsB0, arow, brow, kg, sw, af, bfr);
        mfma_frags<4, 2>(af, bfr, acc);
        waitvm<0>();
        __builtin_amdgcn_s_barrier();
        read_frags<4, 2>(lsA1, lsB1, arow, brow, kg, sw, af, bfr);
        mfma_frags<4, 2>(af, bfr, acc);
    }

#pragma unroll
    for (int j = 0; j < 2; ++j) {
        const int col = col0 + wcol * 32 + j * 16 + l16;
        const int ty = col / DIM;
        const int hh = (col % DIM) >> 6;
        const int dd = col & 63;
        const float bv = bias[col];
        const size_t cbase = ((size_t)(ty * BB * NH) * SS) * HD;
#pragma unroll
        for (int i = 0; i < 4; ++i) {
            const int rbase = row0 + wrow * 64 + i * 16 + kg * 4;
#pragma unroll
            for (int r = 0; r < 4; ++r) {
                const int row = rbase + r;
                const int bq = row >> 11, sq = row & 2047;
                qkvh[cbase + (((size_t)(bq * NH + hh) * SS + sq) << 6) + dd] =
                    f2bf(acc[i][j][r] + bv);
            }
        }
    }
}

// GEMM2: BM=64, BN=128, 512 thr, MF=2, NF=2. NT=12.
// MEASUREMENT (R11): gridDim.z=6 ignored -> 6 identical passes per dispatch.
__global__ __launch_bounds__(512) void gemm_out_kernel(
    const short* __restrict__ A, const short* __restrict__ Bm,
    const float* __restrict__ bias, float* __restrict__ C)
{
    constexpr int K = DIM, N = DIM, NT = 12;
    __shared__ short lsA0[4096], lsB0[8192], lsA1[4096], lsB1[8192];

    const int t    = threadIdx.x;
    const int lane = t & 63;
    const int wid  = t >> 6;
    const int wrow = wid >> 2, wcol = wid & 3;
    const int l16  = lane & 15;
    const int kg   = lane >> 4;
    const int row0 = blockIdx.y * 64;
    const int col0 = blockIdx.x * 128;

    const int srow = t >> 3;
    const int scol = ((t & 7) ^ (srow & 7)) * 8;
    const short* Ab = A  + (size_t)(row0 + srow) * K + scol;
    const short* Bb = Bm + (size_t)(col0 + srow) * K + scol;
    short* ldA0 = lsA0 + t * 8;  short* ldB0 = lsB0 + t * 8;
    short* ldA1 = lsA1 + t * 8;  short* ldB1 = lsB1 + t * 8;
    const int arow = wrow * 32 + l16;
    const int brow = wcol * 32 + l16;
    const int sw   = (l16 & 7) * 8;

    f32x4 acc[2][2];
#pragma unroll
    for (int i = 0; i < 2; ++i)
#pragma unroll
        for (int j = 0; j < 2; ++j) acc[i][j] = (f32x4){0.f, 0.f, 0.f, 0.f};

    stage_op<64>(Ab, K, 0, ldA0);
    stage_op<128>(Bb, K, 0, ldB0);
    stage_op<64>(Ab, K, 64, ldA1);
    stage_op<128>(Bb, K, 64, ldB1);
    waitvm<3>();
    __builtin_amdgcn_s_barrier();

#pragma unroll
    for (int kt = 0; kt < NT - 2; kt += 2) {
        phase_steady<2, 2, 64, 128, 3>(lsA0, lsB0, ldA0, ldB0, Ab, Bb, K,
                                       (kt + 2) * 64, arow, brow, kg, sw, acc);
        phase_steady<2, 2, 64, 128, 3>(lsA1, lsB1, ldA1, ldB1, Ab, Bb, K,
                                       (kt + 3) * 64, arow, brow, kg, sw, acc);
    }
    {
        bf16x8 af[2][2], bfr[2][2];
        read_frags<2, 2>(lsA0, lsB0, arow, brow, kg, sw, af, bfr);
        mfma_frags<2, 2>(af, bfr, acc);
        waitvm<0>();
        __builtin_amdgcn_s_barrier();
        read_frags<2, 2>(lsA1, lsB1, arow, brow, kg, sw, af, bfr);
        mfma_frags<2, 2>(af, bfr, acc);
    }

#pragma unroll
    for (int j = 0; j < 2; ++j) {
        const int col = col0 + wcol * 32 + j * 16 + l16;
        const float bv = bias[col];
#pragma unroll
        for (int i = 0; i < 2; ++i) {
            const int rbase = row0 + wrow * 32 + i * 16 + kg * 4;
#pragma unroll
            for (int r = 0; r < 4; ++r)
                C[(size_t)(rbase + r) * N + col] = acc[i][j][r] + bv;
        }
    }
}

// Sparse Fibonacci attention — R8 low-VGPR two-pass variant (known-best).
// MEASUREMENT (R11): grid = 12288 = 8 replicas; idx = blockIdx.x % 1536
// (1536 % 8 == 0 keeps idx%8 == blockIdx.x%8, so XCD pinning is identical
// per replica). Replicas write identical bytes -> deterministic output.
__global__ __launch_bounds__(256) void fib_attn_kernel(
    const short* __restrict__ qkvh, short* __restrict__ attn)
{
    const int idx   = blockIdx.x % 1536;   // logical block
    const int j     = idx >> 3;            // [0,192)
    const int bh    = (idx & 7) + 8 * (j >> 6);   // [0,24), pinned per XCD
    const int chunk = j & 63;              // [0,64)
    const int wid   = threadIdx.x >> 6;
    const int lane  = threadIdx.x & 63;
    const int ql    = lane >> 3;
    const int c     = lane & 7;
    const int s     = chunk * 32 + wid * 8 + ql;
    const int b = bh / NH, h = bh % NH;

    constexpr size_t TYB = (size_t)BB * NH * SS * HD;
    const size_t base = ((size_t)bh * SS) << 6;
    const short* Kp = qkvh + TYB + base;
    const short* Vp = qkvh + 2 * TYB + base;

    float qv[8];
    {
        bf16x8 v = *(const bf16x8*)(qkvh + base + ((size_t)s << 6) + c * 8);
#pragma unroll
        for (int e = 0; e < 8; ++e) qv[e] = bf2f(v[e]);
    }

    constexpr int NF = 17;
    const int fib[NF] = {0, 1, 2, 3, 5, 8, 13, 21, 34, 55, 89, 144,
                         233, 377, 610, 987, 1597};
    float sc[NF];
#pragma unroll
    for (int f = 0; f < NF; ++f) {
        const bool ok = (fib[f] <= s);
        const int sk = ok ? s - fib[f] : s;
        bf16x8 kv = *(const bf16x8*)(Kp + ((size_t)sk << 6) + c * 8);
        float part = 0.f;
#pragma unroll
        for (int e = 0; e < 8; ++e) part += qv[e] * bf2f(kv[e]);
        part += __shfl_xor(part, 1, 64);
        part += __shfl_xor(part, 2, 64);
        part += __shfl_xor(part, 4, 64);
        sc[f] = ok ? part * 0.125f : -1e30f;
    }

    float mx = sc[0];
#pragma unroll
    for (int f = 1; f < NF; ++f) mx = fmaxf(mx, sc[f]);
    float den = 0.f;
#pragma unroll
    for (int f = 0; f < NF; ++f) { sc[f] = __expf(sc[f] - mx); den += sc[f]; }

    float o[8];
#pragma unroll
    for (int e = 0; e < 8; ++e) o[e] = 0.f;
#pragma unroll
    for (int f = 0; f < NF; ++f) {
        const int sk = (fib[f] <= s) ? s - fib[f] : s;
        bf16x8 vv = *(const bf16x8*)(Vp + ((size_t)sk << 6) + c * 8);
        const float w = sc[f];
#pragma unroll
        for (int e = 0; e < 8; ++e) o[e] += w * bf2f(vv[e]);
    }

    const float inv = 1.f / den;
    short8 r;
#pragma unroll
    for (int e = 0; e < 8; ++e) r[e] = f2bf(o[e] * inv);
    *(short8*)(attn + (size_t)(b * SS + s) * DIM + h * HD + c * 8) = r;
}

extern "C" void kernel_launch(void* const* d_in, const int* in_sizes, int n_in,
                              void* d_out, int out_size, void* d_ws, size_t ws_size,
                              hipStream_t stream)
{
    const float* x     = (const float*)d_in[0];
    const float* w_qkv = (const float*)d_in[1];
    const float* b_qkv = (const float*)d_in[2];
    const float* w_out = (const float*)d_in[3];
    const float* b_out = (const float*)d_in[4];
    float* out = (float*)d_out;

    short* qkvh  = (short*)d_ws;                              // [3][2][12][2048][64] bf16
    short* attnb = (short*)((char*)d_ws + 18874368);          // [4096][768] bf16
    short* xb    = (short*)((char*)d_ws + 25165824);          // [4096][768] bf16
    short* wqkvb = (short*)((char*)d_ws + 31457280);          // [2304][768] bf16
    short* woutb = (short*)((char*)d_ws + 34996224);          // [768][768]  bf16

    conv_kernel<<<dim3(2688, 1, 1), dim3(256, 1, 1), 0, stream>>>(
        x, xb, w_qkv, wqkvb, w_out, woutb);

    // R11 measurement: z=4 replication (identical work per z-slice)
    gemm_qkv_kernel<<<dim3(QKVN / 128, MM / 128, 4), dim3(512, 1, 1), 0, stream>>>(
        xb, wqkvb, b_qkv, qkvh);

    // R11 measurement: 8 replicas
    fib_attn_kernel<<<dim3(12288, 1, 1), dim3(256, 1, 1), 0, stream>>>(qkvh, attnb);

    // R11 measurement: z=6 replication
    gemm_out_kernel<<<dim3(DIM / 128, MM / 64, 6), dim3(512, 1, 1), 0, stream>>>(
        attnb, woutb, b_out, out);
}

// Round 12
// 83.115 us; speedup vs baseline: 2.4699x; 2.4699x over previous
//
#include <hip/hip_runtime.h>
#include <hip/hip_bf16.h>

#define DIM   768
#define NH    12
#define HD    64
#define BB    2
#define SS    2048
#define QKVN  (3 * DIM)   // 2304
#define MM    (BB * SS)   // 4096

typedef __attribute__((ext_vector_type(8))) short bf16x8;
typedef __attribute__((ext_vector_type(8))) short short8;
typedef __attribute__((ext_vector_type(4))) float f32x4;

__device__ __forceinline__ short f2bf(float f) {
    unsigned int u = __float_as_uint(f);
    unsigned int r = (u + 0x7FFFu + ((u >> 16) & 1u)) >> 16;
    return (short)r;
}
__device__ __forceinline__ float bf2f(short s) {
    return __uint_as_float((unsigned int)(unsigned short)s << 16);
}

// packed RNE fp32->bf16 (hardware cvt; m214v22-verified on gfx950)
__device__ __forceinline__ unsigned cvtpk(float lo, float hi) {
    unsigned r;
    asm("v_cvt_pk_bf16_f32 %0, %1, %2" : "=v"(r) : "v"(lo), "v"(hi));
    return r;
}
// one ds_write_b128: 8 bf16 from two float4
__device__ __forceinline__ void wr16(short* dst, float4 a, float4 b) {
    int4 v;
    v.x = (int)cvtpk(a.x, a.y); v.y = (int)cvtpk(a.z, a.w);
    v.z = (int)cvtpk(b.x, b.y); v.w = (int)cvtpk(b.z, b.w);
    *(int4*)dst = v;
}

__device__ __forceinline__ void gld16(const short* g, short* l) {
    __builtin_amdgcn_global_load_lds(
        (const __attribute__((address_space(1))) void*)g,
        (__attribute__((address_space(3))) void*)l, 16, 0, 0);
}

template<int N> __device__ __forceinline__ void waitvm() {
    if constexpr (N == 0) asm volatile("s_waitcnt vmcnt(0)" ::: "memory");
    else if constexpr (N == 4) asm volatile("s_waitcnt vmcnt(4)" ::: "memory");
    else if constexpr (N == 5) asm volatile("s_waitcnt vmcnt(5)" ::: "memory");
    else if constexpr (N == 8) asm volatile("s_waitcnt vmcnt(8)" ::: "memory");
}

// ---------------- shared GEMM fragment helpers (R8-proven) ----------------

template<int RT>
__device__ __forceinline__ void stage_op(const short* gb, int K, int k0, short* ld)
{
#pragma unroll
    for (int ii = 0; ii < RT / 64; ++ii)
        gld16(gb + (size_t)(64 * ii) * K + k0, ld + ii * 4096);
}

template<int MF, int NF>
__device__ __forceinline__ void read_frags(
    const short* lsA, const short* lsB, int arow, int brow, int kg, int sw,
    bf16x8 af[2][MF], bf16x8 bfr[2][NF])
{
#pragma unroll
    for (int kk = 0; kk < 2; ++kk) {
        const int ko = (kk * 32 + kg * 8) ^ sw;
#pragma unroll
        for (int i = 0; i < MF; ++i)
            af[kk][i] = *(const bf16x8*)&lsA[(arow + i * 16) * 64 + ko];
#pragma unroll
        for (int j = 0; j < NF; ++j)
            bfr[kk][j] = *(const bf16x8*)&lsB[(brow + j * 16) * 64 + ko];
    }
}

template<int MF, int NF>
__device__ __forceinline__ void mfma_frags(
    bf16x8 af[2][MF], bf16x8 bfr[2][NF], f32x4 acc[MF][NF])
{
#pragma unroll
    for (int kk = 0; kk < 2; ++kk)
#pragma unroll
        for (int i = 0; i < MF; ++i)
#pragma unroll
            for (int j = 0; j < NF; ++j)
                acc[i][j] = __builtin_amdgcn_mfma_f32_16x16x32_bf16(
                    af[kk][i], bfr[kk][j], acc[i][j], 0, 0, 0);
}

// ---------------- GEMM1: fused fp32->bf16 staging, 128x128, NT=12 ----------
// Phase t: read frags (tile t) ; lgkm0 ; barrier ; issue fp32 loads t+2 ;
// vmcnt(8) [retires t+1 only] ; cvt+ds_write t+1 ; MFMA ; lgkm0 ; barrier.
template<bool ISSUE, bool WRITE, int VC>
__device__ __forceinline__ void g1_phase(
    const short* lsRA, const short* lsRB, short* lsWA, short* lsWB,
    const float* Ag, const float* Bg, int knext,
    float4* sI, const float4* sW, int wr0, int wr1,
    int arow, int brow, int kg, int sw, f32x4 acc[4][2])
{
    bf16x8 af[2][4], bfr[2][2];
    read_frags<4, 2>(lsRA, lsRB, arow, brow, kg, sw, af, bfr);
    asm volatile("s_waitcnt lgkmcnt(0)" ::: "memory");
    __builtin_amdgcn_s_barrier();
    if (ISSUE) {
#pragma unroll
        for (int w = 0; w < 4; ++w) sI[w]     = *(const float4*)(Ag + knext + w * 4);
#pragma unroll
        for (int w = 0; w < 4; ++w) sI[4 + w] = *(const float4*)(Bg + knext + w * 4);
    }
    if (WRITE) {
        waitvm<VC>();
        wr16((short*)lsWA + wr0, sW[0], sW[1]);
        wr16((short*)lsWA + wr1, sW[2], sW[3]);
        wr16((short*)lsWB + wr0, sW[4], sW[5]);
        wr16((short*)lsWB + wr1, sW[6], sW[7]);
    }
    mfma_frags<4, 2>(af, bfr, acc);
    asm volatile("s_waitcnt lgkmcnt(0)" ::: "memory");
    __builtin_amdgcn_s_barrier();
}

__global__ __launch_bounds__(512) void gemm_qkv_kernel(
    const float* __restrict__ A, const float* __restrict__ Bm,
    const float* __restrict__ bias, short* __restrict__ qkvh)
{
    constexpr int K = DIM, NT = 12;
    __shared__ short lsA0[8192], lsB0[8192], lsA1[8192], lsB1[8192];

    const int t    = threadIdx.x;
    const int lane = t & 63;
    const int wid  = t >> 6;
    const int wrow = wid >> 2, wcol = wid & 3;
    const int l16  = lane & 15;
    const int kg   = lane >> 4;

    // XCD row-pinning: 576 blocks, 4 row-blocks per XCD (A panel stays in L2)
    const int bid = blockIdx.x;
    const int jj  = bid >> 3;
    const int row0 = ((bid & 7) * 4 + jj / 18) * 128;
    const int col0 = (jj % 18) * 128;

    // fp32 staging coords: thread covers row t>>2, f32 cols (t&3)*16..+16
    const int srow = t >> 2;
    const int sc4  = (t & 3) * 16;
    const float* Ag = A  + (size_t)(row0 + srow) * K + sc4;
    const float* Bg = Bm + (size_t)(col0 + srow) * K + sc4;
    // LDS write offsets (short units), XOR-swizzled per 8-col chunk
    const int wr0 = srow * 64 + ((((t & 3) * 2 + 0) ^ (srow & 7)) * 8);
    const int wr1 = srow * 64 + ((((t & 3) * 2 + 1) ^ (srow & 7)) * 8);

    const int arow = wrow * 64 + l16;
    const int brow = wcol * 32 + l16;
    const int sw   = (l16 & 7) * 8;

    f32x4 acc[4][2];
#pragma unroll
    for (int i = 0; i < 4; ++i)
#pragma unroll
        for (int j = 0; j < 2; ++j) acc[i][j] = (f32x4){0.f, 0.f, 0.f, 0.f};

    float4 s0[8], s1[8];
    // prologue: t0 -> s0, t1 -> s1; write t0 to buf0
#pragma unroll
    for (int w = 0; w < 4; ++w) s0[w]     = *(const float4*)(Ag + 0 + w * 4);
#pragma unroll
    for (int w = 0; w < 4; ++w) s0[4 + w] = *(const float4*)(Bg + 0 + w * 4);
#pragma unroll
    for (int w = 0; w < 4; ++w) s1[w]     = *(const float4*)(Ag + 64 + w * 4);
#pragma unroll
    for (int w = 0; w < 4; ++w) s1[4 + w] = *(const float4*)(Bg + 64 + w * 4);
    waitvm<8>();                              // t0 landed; t1 in flight
    wr16(lsA0 + wr0, s0[0], s0[1]);
    wr16(lsA0 + wr1, s0[2], s0[3]);
    wr16(lsB0 + wr0, s0[4], s0[5]);
    wr16(lsB0 + wr1, s0[6], s0[7]);
    asm volatile("s_waitcnt lgkmcnt(0)" ::: "memory");
    __builtin_amdgcn_s_barrier();

#pragma unroll
    for (int kt = 0; kt < 10; kt += 2) {
        g1_phase<true, true, 8>(lsA0, lsB0, lsA1, lsB1, Ag, Bg, (kt + 2) * 64,
                                s0, s1, wr0, wr1, arow, brow, kg, sw, acc);
        g1_phase<true, true, 8>(lsA1, lsB1, lsA0, lsB0, Ag, Bg, (kt + 3) * 64,
                                s1, s0, wr0, wr1, arow, brow, kg, sw, acc);
    }
    // t=10: no issue; drain t11 loads, write them to buf1
    g1_phase<false, true, 0>(lsA0, lsB0, lsA1, lsB1, Ag, Bg, 0,
                             s0, s1, wr0, wr1, arow, brow, kg, sw, acc);
    // t=11: pure compute
    {
        bf16x8 af[2][4], bfr[2][2];
        read_frags<4, 2>(lsA1, lsB1, arow, brow, kg, sw, af, bfr);
        mfma_frags<4, 2>(af, bfr, acc);
    }

    // epilogue: head-split bf16 qkvh[type][b][h][s][d] + bias
#pragma unroll
    for (int j = 0; j < 2; ++j) {
        const int col = col0 + wcol * 32 + j * 16 + l16;
        const int ty = col / DIM;
        const int hh = (col % DIM) >> 6;
        const int dd = col & 63;
        const float bv = bias[col];
        const size_t cbase = ((size_t)(ty * BB * NH) * SS) * HD;
#pragma unroll
        for (int i = 0; i < 4; ++i) {
            const int rbase = row0 + wrow * 64 + i * 16 + kg * 4;
#pragma unroll
            for (int r = 0; r < 4; ++r) {
                const int row = rbase + r;
                const int bq = row >> 11, sq = row & 2047;
                qkvh[cbase + (((size_t)(bq * NH + hh) * SS + sq) << 6) + dd] =
                    f2bf(acc[i][j][r] + bv);
            }
        }
    }
}

// ---------------- GEMM2: A bf16 gld_lds + B fp32 reg-staged, 64x128 --------
template<bool ISSUE, bool WRITE, int VC>
__device__ __forceinline__ void g2_phase(
    const short* lsRA, const short* lsRB, short* lsWB,
    const short* Agb, const float* Bg, int knext, short* ldA,
    float4* sI, const float4* sW, int wr0, int wr1,
    int arow, int brow, int kg, int sw, f32x4 acc[2][2])
{
    bf16x8 af[2][2], bfr[2][2];
    read_frags<2, 2>(lsRA, lsRB, arow, brow, kg, sw, af, bfr);
    asm volatile("s_waitcnt lgkmcnt(0)" ::: "memory");
    __builtin_amdgcn_s_barrier();
    if (ISSUE) {
        stage_op<64>(Agb, DIM, knext, ldA);   // A tile t+2 -> just-read buffer
#pragma unroll
        for (int w = 0; w < 4; ++w) sI[w] = *(const float4*)(Bg + knext + w * 4);
    }
    if (WRITE) {
        waitvm<VC>();
        wr16((short*)lsWB + wr0, sW[0], sW[1]);
        wr16((short*)lsWB + wr1, sW[2], sW[3]);
    }
    mfma_frags<2, 2>(af, bfr, acc);
    asm volatile("s_waitcnt lgkmcnt(0)" ::: "memory");
    __builtin_amdgcn_s_barrier();
}

__global__ __launch_bounds__(512) void gemm_out_kernel(
    const short* __restrict__ A, const float* __restrict__ Bm,
    const float* __restrict__ bias, float* __restrict__ C)
{
    constexpr int K = DIM, N = DIM;
    __shared__ short lsA0[4096], lsB0[8192], lsA1[4096], lsB1[8192];

    const int t    = threadIdx.x;
    const int lane = t & 63;
    const int wid  = t >> 6;
    const int wrow = wid >> 2, wcol = wid & 3;
    const int l16  = lane & 15;
    const int kg   = lane >> 4;

    // XCD row-pinning: 384 blocks, 8 row-blocks per XCD
    const int bid = blockIdx.x;
    const int jj  = bid >> 3;
    const int row0 = ((bid & 7) * 8 + jj / 6) * 64;
    const int col0 = (jj % 6) * 128;

    // A (bf16) gld_lds staging, pre-swizzled source (R8 pattern)
    const int sra  = t >> 3;
    const int scaa = ((t & 7) ^ (sra & 7)) * 8;
    const short* Agb = A + (size_t)(row0 + sra) * K + scaa;
    short* ldA0 = lsA0 + t * 8;
    short* ldA1 = lsA1 + t * 8;

    // B (fp32 w_out) reg staging
    const int srow = t >> 2;
    const int sc4  = (t & 3) * 16;
    const float* Bg = Bm + (size_t)(col0 + srow) * K + sc4;
    const int wr0 = srow * 64 + ((((t & 3) * 2 + 0) ^ (srow & 7)) * 8);
    const int wr1 = srow * 64 + ((((t & 3) * 2 + 1) ^ (srow & 7)) * 8);

    const int arow = wrow * 32 + l16;
    const int brow = wcol * 32 + l16;
    const int sw   = (l16 & 7) * 8;

    f32x4 acc[2][2];
#pragma unroll
    for (int i = 0; i < 2; ++i)
#pragma unroll
        for (int j = 0; j < 2; ++j) acc[i][j] = (f32x4){0.f, 0.f, 0.f, 0.f};

    float4 s0[4], s1[4];
    // prologue: A t0->lsA0, A t1->lsA1 (gld_lds); B t0->s0, B t1->s1
    stage_op<64>(Agb, K, 0, ldA0);
    stage_op<64>(Agb, K, 64, ldA1);
#pragma unroll
    for (int w = 0; w < 4; ++w) s0[w] = *(const float4*)(Bg + 0 + w * 4);
#pragma unroll
    for (int w = 0; w < 4; ++w) s1[w] = *(const float4*)(Bg + 64 + w * 4);
    waitvm<4>();                       // retires A0, A1, B0 (leaves B1 in flight)
    wr16(lsB0 + wr0, s0[0], s0[1]);
    wr16(lsB0 + wr1, s0[2], s0[3]);
    asm volatile("s_waitcnt lgkmcnt(0)" ::: "memory");
    __builtin_amdgcn_s_barrier();

#pragma unroll
    for (int kt = 0; kt < 10; kt += 2) {
        g2_phase<true, true, 5>(lsA0, lsB0, lsB1, Agb, Bg, (kt + 2) * 64, ldA0,
                                s0, s1, wr0, wr1, arow, brow, kg, sw, acc);
        g2_phase<true, true, 5>(lsA1, lsB1, lsB0, Agb, Bg, (kt + 3) * 64, ldA1,
                                s1, s0, wr0, wr1, arow, brow, kg, sw, acc);
    }
    g2_phase<false, true, 0>(lsA0, lsB0, lsB1, Agb, Bg, 0, ldA0,
                             s0, s1, wr0, wr1, arow, brow, kg, sw, acc);
    {
        bf16x8 af[2][2], bfr[2][2];
        read_frags<2, 2>(lsA1, lsB1, arow, brow, kg, sw, af, bfr);
        mfma_frags<2, 2>(af, bfr, acc);
    }

#pragma unroll
    for (int j = 0; j < 2; ++j) {
        const int col = col0 + wcol * 32 + j * 16 + l16;
        const float bv = bias[col];
#pragma unroll
        for (int i = 0; i < 2; ++i) {
            const int rbase = row0 + wrow * 32 + i * 16 + kg * 4;
#pragma unroll
            for (int r = 0; r < 4; ++r)
                C[(size_t)(rbase + r) * N + col] = acc[i][j][r] + bv;
        }
    }
}

// Sparse Fibonacci attention — R8 two-pass, wave = 8 queries, 8 lanes/query.
__global__ __launch_bounds__(256) void fib_attn_kernel(
    const short* __restrict__ qkvh, short* __restrict__ attn)
{
    const int idx   = blockIdx.x;          // [0,1536)
    const int j     = idx >> 3;            // [0,192)
    const int bh    = (idx & 7) + 8 * (j >> 6);   // [0,24), pinned per XCD
    const int chunk = j & 63;              // [0,64)
    const int wid   = threadIdx.x >> 6;
    const int lane  = threadIdx.x & 63;
    const int ql    = lane >> 3;
    const int c     = lane & 7;
    const int s     = chunk * 32 + wid * 8 + ql;
    const int b = bh / NH, h = bh % NH;

    constexpr size_t TYB = (size_t)BB * NH * SS * HD;
    const size_t base = ((size_t)bh * SS) << 6;
    const short* Kp = qkvh + TYB + base;
    const short* Vp = qkvh + 2 * TYB + base;

    float qv[8];
    {
        bf16x8 v = *(const bf16x8*)(qkvh + base + ((size_t)s << 6) + c * 8);
#pragma unroll
        for (int e = 0; e < 8; ++e) qv[e] = bf2f(v[e]);
    }

    constexpr int NF = 17;
    const int fib[NF] = {0, 1, 2, 3, 5, 8, 13, 21, 34, 55, 89, 144,
                         233, 377, 610, 987, 1597};
    float sc[NF];
#pragma unroll
    for (int f = 0; f < NF; ++f) {
        const bool ok = (fib[f] <= s);
        const int sk = ok ? s - fib[f] : s;
        bf16x8 kv = *(const bf16x8*)(Kp + ((size_t)sk << 6) + c * 8);
        float part = 0.f;
#pragma unroll
        for (int e = 0; e < 8; ++e) part += qv[e] * bf2f(kv[e]);
        part += __shfl_xor(part, 1, 64);
        part += __shfl_xor(part, 2, 64);
        part += __shfl_xor(part, 4, 64);
        sc[f] = ok ? part * 0.125f : -1e30f;
    }

    float mx = sc[0];
#pragma unroll
    for (int f = 1; f < NF; ++f) mx = fmaxf(mx, sc[f]);
    float den = 0.f;
#pragma unroll
    for (int f = 0; f < NF; ++f) { sc[f] = __expf(sc[f] - mx); den += sc[f]; }

    float o[8];
#pragma unroll
    for (int e = 0; e < 8; ++e) o[e] = 0.f;
#pragma unroll
    for (int f = 0; f < NF; ++f) {
        const int sk = (fib[f] <= s) ? s - fib[f] : s;
        bf16x8 vv = *(const bf16x8*)(Vp + ((size_t)sk << 6) + c * 8);
        const float w = sc[f];
#pragma unroll
        for (int e = 0; e < 8; ++e) o[e] += w * bf2f(vv[e]);
    }

    const float inv = 1.f / den;
    short8 r;
#pragma unroll
    for (int e = 0; e < 8; ++e) r[e] = f2bf(o[e] * inv);
    *(short8*)(attn + (size_t)(b * SS + s) * DIM + h * HD + c * 8) = r;
}

extern "C" void kernel_launch(void* const* d_in, const int* in_sizes, int n_in,
                              void* d_out, int out_size, void* d_ws, size_t ws_size,
                              hipStream_t stream)
{
    const float* x     = (const float*)d_in[0];
    const float* w_qkv = (const float*)d_in[1];
    const float* b_qkv = (const float*)d_in[2];
    const float* w_out = (const float*)d_in[3];
    const float* b_out = (const float*)d_in[4];
    float* out = (float*)d_out;

    short* qkvh  = (short*)d_ws;                      // [3][2][12][2048][64] bf16
    short* attnb = (short*)((char*)d_ws + 18874368);  // [4096][768] bf16

    // GEMM1 (fused x/w_qkv fp32->bf16): 576 blocks XCD-row-pinned
    gemm_qkv_kernel<<<dim3(576, 1, 1), dim3(512, 1, 1), 0, stream>>>(
        x, w_qkv, b_qkv, qkvh);

    fib_attn_kernel<<<dim3(1536, 1, 1), dim3(256, 1, 1), 0, stream>>>(qkvh, attnb);

    // GEMM2 (fused w_out fp32->bf16): 384 blocks XCD-row-pinned
    gemm_out_kernel<<<dim3(384, 1, 1), dim3(512, 1, 1), 0, stream>>>(
        attnb, w_out, b_out, out);
}

// Round 13
// 70.121 us; speedup vs baseline: 2.9276x; 1.1853x over previous
//
#include <hip/hip_runtime.h>
#include <hip/hip_bf16.h>

#define DIM   768
#define NH    12
#define HD    64
#define BB    2
#define SS    2048
#define QKVN  (3 * DIM)   // 2304
#define MM    (BB * SS)   // 4096

typedef __attribute__((ext_vector_type(8))) short bf16x8;
typedef __attribute__((ext_vector_type(8))) short short8;
typedef __attribute__((ext_vector_type(4))) float f32x4;

__device__ __forceinline__ short f2bf(float f) {
    unsigned int u = __float_as_uint(f);
    unsigned int r = (u + 0x7FFFu + ((u >> 16) & 1u)) >> 16;
    return (short)r;
}
__device__ __forceinline__ float bf2f(short s) {
    return __uint_as_float((unsigned int)(unsigned short)s << 16);
}

// packed RNE fp32->bf16 (bit-identical to f2bf; numerics validated R12)
__device__ __forceinline__ unsigned cvtpk(float lo, float hi) {
    unsigned r;
    asm("v_cvt_pk_bf16_f32 %0, %1, %2" : "=v"(r) : "v"(lo), "v"(hi));
    return r;
}
__device__ __forceinline__ void wr16(short* dst, float4 a, float4 b) {
    int4 v;
    v.x = (int)cvtpk(a.x, a.y); v.y = (int)cvtpk(a.z, a.w);
    v.z = (int)cvtpk(b.x, b.y); v.w = (int)cvtpk(b.z, b.w);
    *(int4*)dst = v;
}

__device__ __forceinline__ void gld16(const short* g, short* l) {
    __builtin_amdgcn_global_load_lds(
        (const __attribute__((address_space(1))) void*)g,
        (__attribute__((address_space(3))) void*)l, 16, 0, 0);
}

template<int N> __device__ __forceinline__ void waitvm() {
    if constexpr (N == 0) asm volatile("s_waitcnt vmcnt(0)" ::: "memory");
    else if constexpr (N == 3) asm volatile("s_waitcnt vmcnt(3)" ::: "memory");
    else if constexpr (N == 4) asm volatile("s_waitcnt vmcnt(4)" ::: "memory");
    else if constexpr (N == 6) asm volatile("s_waitcnt vmcnt(6)" ::: "memory");
    else if constexpr (N == 8) asm volatile("s_waitcnt vmcnt(8)" ::: "memory");
}

// fp32 -> bf16 for WEIGHTS only (w_qkv, w_out); 294912 groups = 1152 blocks
__global__ __launch_bounds__(256) void conv_w_kernel(
    const float* __restrict__ wq, short* __restrict__ wqb,
    const float* __restrict__ wo, short* __restrict__ wob)
{
    const int nq = (QKVN * DIM) / 8;   // 221184
    int i8 = blockIdx.x * 256 + threadIdx.x;
    const float* src; short* dst;
    if (i8 < nq) { src = wq; dst = wqb; }
    else         { i8 -= nq; src = wo; dst = wob; }
    const float4* p = (const float4*)src + (size_t)i8 * 2;
    float4 a = p[0], b = p[1];
    short8 r;
    r[0] = f2bf(a.x); r[1] = f2bf(a.y); r[2] = f2bf(a.z); r[3] = f2bf(a.w);
    r[4] = f2bf(b.x); r[5] = f2bf(b.y); r[6] = f2bf(b.z); r[7] = f2bf(b.w);
    *((short8*)dst + i8) = r;
}

// ---------------- shared GEMM fragment helpers (R8-proven) ----------------

template<int RT>
__device__ __forceinline__ void stage_op(const short* gb, int K, int k0, short* ld)
{
#pragma unroll
    for (int ii = 0; ii < RT / 64; ++ii)
        gld16(gb + (size_t)(64 * ii) * K + k0, ld + ii * 4096);
}

template<int MF, int NF>
__device__ __forceinline__ void read_frags(
    const short* lsA, const short* lsB, int arow, int brow, int kg, int sw,
    bf16x8 af[2][MF], bf16x8 bfr[2][NF])
{
#pragma unroll
    for (int kk = 0; kk < 2; ++kk) {
        const int ko = (kk * 32 + kg * 8) ^ sw;
#pragma unroll
        for (int i = 0; i < MF; ++i)
            af[kk][i] = *(const bf16x8*)&lsA[(arow + i * 16) * 64 + ko];
#pragma unroll
        for (int j = 0; j < NF; ++j)
            bfr[kk][j] = *(const bf16x8*)&lsB[(brow + j * 16) * 64 + ko];
    }
}

template<int MF, int NF>
__device__ __forceinline__ void mfma_frags(
    bf16x8 af[2][MF], bf16x8 bfr[2][NF], f32x4 acc[MF][NF])
{
#pragma unroll
    for (int kk = 0; kk < 2; ++kk)
#pragma unroll
        for (int i = 0; i < MF; ++i)
#pragma unroll
            for (int j = 0; j < NF; ++j)
                acc[i][j] = __builtin_amdgcn_mfma_f32_16x16x32_bf16(
                    af[kk][i], bfr[kk][j], acc[i][j], 0, 0, 0);
}

template<int MF, int NF, int ART, int BRT, int VC>
__device__ __forceinline__ void phase_steady(
    const short* lsA, const short* lsB, short* ldA, short* ldB,
    const short* Ab, const short* Bb, int K, int knext,
    int arow, int brow, int kg, int sw, f32x4 acc[MF][NF])
{
    bf16x8 af[2][MF], bfr[2][NF];
    read_frags<MF, NF>(lsA, lsB, arow, brow, kg, sw, af, bfr);
    asm volatile("s_waitcnt lgkmcnt(0)" ::: "memory");
    __builtin_amdgcn_s_barrier();
    stage_op<ART>(Ab, K, knext, ldA);
    stage_op<BRT>(Bb, K, knext, ldB);
    mfma_frags<MF, NF>(af, bfr, acc);
    waitvm<VC>();
    __builtin_amdgcn_s_barrier();
}

// ------- GEMM1: A = x fp32 (fused cvt, reg-staged NAMED scalars), B bf16 ----
// Phase: read frags; lgkm0; barrier; issue A t+2 (4 ld) + B t+2 (2 gld_lds);
// vmcnt(8) [retires A t+1]; cvt+ds_write A t+1 -> other buf; MFMA;
// vmcnt(6) [retires B t+1]; lgkm0; barrier.
#define G1_STEADY(lsRA, lsRB, LDB, lsWA, I, W, KN)                           \
    {                                                                         \
        bf16x8 af[2][4], bfr[2][2];                                           \
        read_frags<4, 2>(lsRA, lsRB, arow, brow, kg, sw, af, bfr);            \
        asm volatile("s_waitcnt lgkmcnt(0)" ::: "memory");                    \
        __builtin_amdgcn_s_barrier();                                         \
        I##0 = *(const float4*)(Ag + (KN));                                   \
        I##1 = *(const float4*)(Ag + (KN) + 4);                               \
        I##2 = *(const float4*)(Ag + (KN) + 8);                               \
        I##3 = *(const float4*)(Ag + (KN) + 12);                              \
        stage_op<128>(Bb, DIM, (KN), LDB);                                    \
        waitvm<8>();                                                          \
        wr16(lsWA + wr0, W##0, W##1);                                         \
        wr16(lsWA + wr1, W##2, W##3);                                         \
        mfma_frags<4, 2>(af, bfr, acc);                                       \
        waitvm<6>();                                                          \
        asm volatile("s_waitcnt lgkmcnt(0)" ::: "memory");                    \
        __builtin_amdgcn_s_barrier();                                         \
    }

__global__ __launch_bounds__(512, 4) void gemm_qkv_kernel(
    const float* __restrict__ A, const short* __restrict__ Bm,
    const float* __restrict__ bias, short* __restrict__ qkvh)
{
    constexpr int K = DIM;
    __shared__ short lsA0[8192], lsB0[8192], lsA1[8192], lsB1[8192];

    const int t    = threadIdx.x;
    const int lane = t & 63;
    const int wid  = t >> 6;
    const int wrow = wid >> 2, wcol = wid & 3;
    const int l16  = lane & 15;
    const int kg   = lane >> 4;

    // XCD row-pinning (bijective, R12-verified): A panels stay in one L2
    const int bid = blockIdx.x;
    const int jj  = bid >> 3;
    const int row0 = ((bid & 7) * 4 + jj / 18) * 128;
    const int col0 = (jj % 18) * 128;

    // A fp32 staging: thread covers row t>>2, fp32 cols (t&3)*16..+16
    const int srow = t >> 2;
    const float* Ag = A + (size_t)(row0 + srow) * K + (t & 3) * 16;
    const int wr0 = srow * 64 + ((((t & 3) * 2 + 0) ^ (srow & 7)) * 8);
    const int wr1 = srow * 64 + ((((t & 3) * 2 + 1) ^ (srow & 7)) * 8);

    // B bf16 gld_lds staging (R8 pattern, pre-swizzled source)
    const int srb = t >> 3;
    const short* Bb = Bm + (size_t)(col0 + srb) * K + ((t & 7) ^ (srb & 7)) * 8;
    short* ldB0 = lsB0 + t * 8;
    short* ldB1 = lsB1 + t * 8;

    const int arow = wrow * 64 + l16;
    const int brow = wcol * 32 + l16;
    const int sw   = (l16 & 7) * 8;

    f32x4 acc[4][2];
#pragma unroll
    for (int i = 0; i < 4; ++i)
#pragma unroll
        for (int j = 0; j < 2; ++j) acc[i][j] = (f32x4){0.f, 0.f, 0.f, 0.f};

    // named scalar staging regs (rule #20: no arrays, no pointer params)
    float4 aP0, aP1, aP2, aP3, aQ0, aQ1, aQ2, aQ3;

    // prologue: A t0 -> aP, B t0 -> lsB0, A t1 -> aQ, B t1 -> lsB1
    aP0 = *(const float4*)(Ag);      aP1 = *(const float4*)(Ag + 4);
    aP2 = *(const float4*)(Ag + 8);  aP3 = *(const float4*)(Ag + 12);
    stage_op<128>(Bb, DIM, 0, ldB0);
    aQ0 = *(const float4*)(Ag + 64); aQ1 = *(const float4*)(Ag + 68);
    aQ2 = *(const float4*)(Ag + 72); aQ3 = *(const float4*)(Ag + 76);
    stage_op<128>(Bb, DIM, 64, ldB1);
    waitvm<8>();                       // A t0 landed
    wr16(lsA0 + wr0, aP0, aP1);
    wr16(lsA0 + wr1, aP2, aP3);
    waitvm<6>();                       // B t0 landed
    asm volatile("s_waitcnt lgkmcnt(0)" ::: "memory");
    __builtin_amdgcn_s_barrier();

    for (int kt = 0; kt < 10; kt += 2) {
        G1_STEADY(lsA0, lsB0, ldB0, lsA1, aP, aQ, (kt + 2) * 64)
        G1_STEADY(lsA1, lsB1, ldB1, lsA0, aQ, aP, (kt + 3) * 64)
    }
    // tail A (tile 10 in buf0; A t11 in aQ, B t11 landing in lsB1)
    {
        bf16x8 af[2][4], bfr[2][2];
        read_frags<4, 2>(lsA0, lsB0, arow, brow, kg, sw, af, bfr);
        asm volatile("s_waitcnt lgkmcnt(0)" ::: "memory");
        __builtin_amdgcn_s_barrier();
        waitvm<0>();
        wr16(lsA1 + wr0, aQ0, aQ1);
        wr16(lsA1 + wr1, aQ2, aQ3);
        mfma_frags<4, 2>(af, bfr, acc);
        asm volatile("s_waitcnt lgkmcnt(0)" ::: "memory");
        __builtin_amdgcn_s_barrier();
    }
    // tail B (tile 11)
    {
        bf16x8 af[2][4], bfr[2][2];
        read_frags<4, 2>(lsA1, lsB1, arow, brow, kg, sw, af, bfr);
        mfma_frags<4, 2>(af, bfr, acc);
    }

    // epilogue: head-split bf16 qkvh[type][b][h][s][d] + bias
#pragma unroll
    for (int j = 0; j < 2; ++j) {
        const int col = col0 + wcol * 32 + j * 16 + l16;
        const int ty = col / DIM;
        const int hh = (col % DIM) >> 6;
        const int dd = col & 63;
        const float bv = bias[col];
        const size_t cbase = ((size_t)(ty * BB * NH) * SS) * HD;
#pragma unroll
        for (int i = 0; i < 4; ++i) {
            const int rbase = row0 + wrow * 64 + i * 16 + kg * 4;
#pragma unroll
            for (int r = 0; r < 4; ++r) {
                const int row = rbase + r;
                const int bq = row >> 11, sq = row & 2047;
                qkvh[cbase + (((size_t)(bq * NH + hh) * SS + sq) << 6) + dd] =
                    f2bf(acc[i][j][r] + bv);
            }
        }
    }
}

// GEMM2: R8-exact. BM=64, BN=128, 512 thr, MF=2, NF=2, grid (6,64). NT=12.
__global__ __launch_bounds__(512) void gemm_out_kernel(
    const short* __restrict__ A, const short* __restrict__ Bm,
    const float* __restrict__ bias, float* __restrict__ C)
{
    constexpr int K = DIM, N = DIM, NT = 12;
    __shared__ short lsA0[4096], lsB0[8192], lsA1[4096], lsB1[8192];

    const int t    = threadIdx.x;
    const int lane = t & 63;
    const int wid  = t >> 6;
    const int wrow = wid >> 2, wcol = wid & 3;
    const int l16  = lane & 15;
    const int kg   = lane >> 4;
    const int row0 = blockIdx.y * 64;
    const int col0 = blockIdx.x * 128;

    const int srow = t >> 3;
    const int scol = ((t & 7) ^ (srow & 7)) * 8;
    const short* Ab = A  + (size_t)(row0 + srow) * K + scol;
    const short* Bb = Bm + (size_t)(col0 + srow) * K + scol;
    short* ldA0 = lsA0 + t * 8;  short* ldB0 = lsB0 + t * 8;
    short* ldA1 = lsA1 + t * 8;  short* ldB1 = lsB1 + t * 8;
    const int arow = wrow * 32 + l16;
    const int brow = wcol * 32 + l16;
    const int sw   = (l16 & 7) * 8;

    f32x4 acc[2][2];
#pragma unroll
    for (int i = 0; i < 2; ++i)
#pragma unroll
        for (int j = 0; j < 2; ++j) acc[i][j] = (f32x4){0.f, 0.f, 0.f, 0.f};

    stage_op<64>(Ab, K, 0, ldA0);
    stage_op<128>(Bb, K, 0, ldB0);
    stage_op<64>(Ab, K, 64, ldA1);
    stage_op<128>(Bb, K, 64, ldB1);
    waitvm<3>();
    __builtin_amdgcn_s_barrier();

#pragma unroll
    for (int kt = 0; kt < NT - 2; kt += 2) {
        phase_steady<2, 2, 64, 128, 3>(lsA0, lsB0, ldA0, ldB0, Ab, Bb, K,
                                       (kt + 2) * 64, arow, brow, kg, sw, acc);
        phase_steady<2, 2, 64, 128, 3>(lsA1, lsB1, ldA1, ldB1, Ab, Bb, K,
                                       (kt + 3) * 64, arow, brow, kg, sw, acc);
    }
    {
        bf16x8 af[2][2], bfr[2][2];
        read_frags<2, 2>(lsA0, lsB0, arow, brow, kg, sw, af, bfr);
        mfma_frags<2, 2>(af, bfr, acc);
        waitvm<0>();
        __builtin_amdgcn_s_barrier();
        read_frags<2, 2>(lsA1, lsB1, arow, brow, kg, sw, af, bfr);
        mfma_frags<2, 2>(af, bfr, acc);
    }

#pragma unroll
    for (int j = 0; j < 2; ++j) {
        const int col = col0 + wcol * 32 + j * 16 + l16;
        const float bv = bias[col];
#pragma unroll
        for (int i = 0; i < 2; ++i) {
            const int rbase = row0 + wrow * 32 + i * 16 + kg * 4;
#pragma unroll
            for (int r = 0; r < 4; ++r)
                C[(size_t)(rbase + r) * N + col] = acc[i][j][r] + bv;
        }
    }
}

// Sparse Fibonacci attention — R8-exact two-pass, wave = 8 q, 8 lanes/q.
__global__ __launch_bounds__(256) void fib_attn_kernel(
    const short* __restrict__ qkvh, short* __restrict__ attn)
{
    const int idx   = blockIdx.x;          // [0,1536)
    const int j     = idx >> 3;            // [0,192)
    const int bh    = (idx & 7) + 8 * (j >> 6);   // [0,24), pinned per XCD
    const int chunk = j & 63;              // [0,64)
    const int wid   = threadIdx.x >> 6;
    const int lane  = threadIdx.x & 63;
    const int ql    = lane >> 3;
    const int c     = lane & 7;
    const int s     = chunk * 32 + wid * 8 + ql;
    const int b = bh / NH, h = bh % NH;

    constexpr size_t TYB = (size_t)BB * NH * SS * HD;
    const size_t base = ((size_t)bh * SS) << 6;
    const short* Kp = qkvh + TYB + base;
    const short* Vp = qkvh + 2 * TYB + base;

    float qv[8];
    {
        bf16x8 v = *(const bf16x8*)(qkvh + base + ((size_t)s << 6) + c * 8);
#pragma unroll
        for (int e = 0; e < 8; ++e) qv[e] = bf2f(v[e]);
    }

    constexpr int NF = 17;
    const int fib[NF] = {0, 1, 2, 3, 5, 8, 13, 21, 34, 55, 89, 144,
                         233, 377, 610, 987, 1597};
    float sc[NF];
#pragma unroll
    for (int f = 0; f < NF; ++f) {
        const bool ok = (fib[f] <= s);
        const int sk = ok ? s - fib[f] : s;
        bf16x8 kv = *(const bf16x8*)(Kp + ((size_t)sk << 6) + c * 8);
        float part = 0.f;
#pragma unroll
        for (int e = 0; e < 8; ++e) part += qv[e] * bf2f(kv[e]);
        part += __shfl_xor(part, 1, 64);
        part += __shfl_xor(part, 2, 64);
        part += __shfl_xor(part, 4, 64);
        sc[f] = ok ? part * 0.125f : -1e30f;
    }

    float mx = sc[0];
#pragma unroll
    for (int f = 1; f < NF; ++f) mx = fmaxf(mx, sc[f]);
    float den = 0.f;
#pragma unroll
    for (int f = 0; f < NF; ++f) { sc[f] = __expf(sc[f] - mx); den += sc[f]; }

    float o[8];
#pragma unroll
    for (int e = 0; e < 8; ++e) o[e] = 0.f;
#pragma unroll
    for (int f = 0; f < NF; ++f) {
        const int sk = (fib[f] <= s) ? s - fib[f] : s;
        bf16x8 vv = *(const bf16x8*)(Vp + ((size_t)sk << 6) + c * 8);
        const float w = sc[f];
#pragma unroll
        for (int e = 0; e < 8; ++e) o[e] += w * bf2f(vv[e]);
    }

    const float inv = 1.f / den;
    short8 r;
#pragma unroll
    for (int e = 0; e < 8; ++e) r[e] = f2bf(o[e] * inv);
    *(short8*)(attn + (size_t)(b * SS + s) * DIM + h * HD + c * 8) = r;
}

extern "C" void kernel_launch(void* const* d_in, const int* in_sizes, int n_in,
                              void* d_out, int out_size, void* d_ws, size_t ws_size,
                              hipStream_t stream)
{
    const float* x     = (const float*)d_in[0];
    const float* w_qkv = (const float*)d_in[1];
    const float* b_qkv = (const float*)d_in[2];
    const float* w_out = (const float*)d_in[3];
    const float* b_out = (const float*)d_in[4];
    float* out = (float*)d_out;

    short* qkvh  = (short*)d_ws;                      // [3][2][12][2048][64] bf16
    short* attnb = (short*)((char*)d_ws + 18874368);  // [4096][768] bf16
    short* wqkvb = (short*)((char*)d_ws + 25165824);  // [2304][768] bf16
    short* woutb = (short*)((char*)d_ws + 28704768);  // [768][768]  bf16

    // weights fp32->bf16 (294912 groups, exact grid)
    conv_w_kernel<<<dim3(1152, 1, 1), dim3(256, 1, 1), 0, stream>>>(
        w_qkv, wqkvb, w_out, woutb);

    // GEMM1: x fp32 direct (fused cvt), B bf16; 576 blocks XCD-row-pinned
    gemm_qkv_kernel<<<dim3(576, 1, 1), dim3(512, 1, 1), 0, stream>>>(
        x, wqkvb, b_qkv, qkvh);

    fib_attn_kernel<<<dim3(1536, 1, 1), dim3(256, 1, 1), 0, stream>>>(qkvh, attnb);

    gemm_out_kernel<<<dim3(6, 64, 1), dim3(512, 1, 1), 0, stream>>>(
        attnb, woutb, b_out, out);
}

// Round 14
// 57.951 us; speedup vs baseline: 3.5424x; 1.2100x over previous
//
#include <hip/hip_runtime.h>
#include <hip/hip_bf16.h>

#define DIM   768
#define NH    12
#define HD    64
#define BB    2
#define SS    2048
#define QKVN  (3 * DIM)   // 2304
#define MM    (BB * SS)   // 4096

typedef __attribute__((ext_vector_type(8))) short bf16x8;
typedef __attribute__((ext_vector_type(8))) short short8;
typedef __attribute__((ext_vector_type(4))) float f32x4;

__device__ __forceinline__ short f2bf(float f) {
    unsigned int u = __float_as_uint(f);
    unsigned int r = (u + 0x7FFFu + ((u >> 16) & 1u)) >> 16;
    return (short)r;
}
__device__ __forceinline__ float bf2f(short s) {
    return __uint_as_float((unsigned int)(unsigned short)s << 16);
}

__device__ __forceinline__ void gld16(const short* g, short* l) {
    __builtin_amdgcn_global_load_lds(
        (const __attribute__((address_space(1))) void*)g,
        (__attribute__((address_space(3))) void*)l, 16, 0, 0);
}

template<int N> __device__ __forceinline__ void waitvm() {
    if constexpr (N == 0) asm volatile("s_waitcnt vmcnt(0)" ::: "memory");
    else if constexpr (N == 3) asm volatile("s_waitcnt vmcnt(3)" ::: "memory");
    else if constexpr (N == 4) asm volatile("s_waitcnt vmcnt(4)" ::: "memory");
}

// fp32 -> bf16 conversion for x, w_qkv, w_out (R8-exact)
__global__ __launch_bounds__(256) void conv_kernel(
    const float* __restrict__ x,  short* __restrict__ xb,
    const float* __restrict__ wq, short* __restrict__ wqb,
    const float* __restrict__ wo, short* __restrict__ wob)
{
    const int nx = (MM * DIM) / 8;
    const int nq = (QKVN * DIM) / 8;
    int i8 = blockIdx.x * 256 + threadIdx.x;
    const float* src; short* dst;
    if (i8 < nx)           { src = x;  dst = xb; }
    else if (i8 < nx + nq) { i8 -= nx; src = wq; dst = wqb; }
    else                   { i8 -= nx + nq; src = wo; dst = wob; }
    const float4* p = (const float4*)src + (size_t)i8 * 2;
    float4 a = p[0], b = p[1];
    short8 r;
    r[0] = f2bf(a.x); r[1] = f2bf(a.y); r[2] = f2bf(a.z); r[3] = f2bf(a.w);
    r[4] = f2bf(b.x); r[5] = f2bf(b.y); r[6] = f2bf(b.z); r[7] = f2bf(b.w);
    *((short8*)dst + i8) = r;
}

// ------------- GEMM core: counted-vmcnt 2-buffer pipeline (R8-exact) -----

template<int RT>
__device__ __forceinline__ void stage_op(const short* gb, int K, int k0, short* ld)
{
#pragma unroll
    for (int ii = 0; ii < RT / 64; ++ii)
        gld16(gb + (size_t)(64 * ii) * K + k0, ld + ii * 4096);
}

template<int MF, int NF>
__device__ __forceinline__ void read_frags(
    const short* lsA, const short* lsB, int arow, int brow, int kg, int sw,
    bf16x8 af[2][MF], bf16x8 bfr[2][NF])
{
#pragma unroll
    for (int kk = 0; kk < 2; ++kk) {
        const int ko = (kk * 32 + kg * 8) ^ sw;
#pragma unroll
        for (int i = 0; i < MF; ++i)
            af[kk][i] = *(const bf16x8*)&lsA[(arow + i * 16) * 64 + ko];
#pragma unroll
        for (int j = 0; j < NF; ++j)
            bfr[kk][j] = *(const bf16x8*)&lsB[(brow + j * 16) * 64 + ko];
    }
}

template<int MF, int NF>
__device__ __forceinline__ void mfma_frags(
    bf16x8 af[2][MF], bf16x8 bfr[2][NF], f32x4 acc[MF][NF])
{
#pragma unroll
    for (int kk = 0; kk < 2; ++kk)
#pragma unroll
        for (int i = 0; i < MF; ++i)
#pragma unroll
            for (int j = 0; j < NF; ++j)
                acc[i][j] = __builtin_amdgcn_mfma_f32_16x16x32_bf16(
                    af[kk][i], bfr[kk][j], acc[i][j], 0, 0, 0);
}

template<int MF, int NF, int ART, int BRT, int VC>
__device__ __forceinline__ void phase_steady(
    const short* lsA, const short* lsB, short* ldA, short* ldB,
    const short* Ab, const short* Bb, int K, int knext,
    int arow, int brow, int kg, int sw, f32x4 acc[MF][NF])
{
    bf16x8 af[2][MF], bfr[2][NF];
    read_frags<MF, NF>(lsA, lsB, arow, brow, kg, sw, af, bfr);
    asm volatile("s_waitcnt lgkmcnt(0)" ::: "memory");
    __builtin_amdgcn_s_barrier();
    stage_op<ART>(Ab, K, knext, ldA);
    stage_op<BRT>(Bb, K, knext, ldB);
    mfma_frags<MF, NF>(af, bfr, acc);
    waitvm<VC>();
    __builtin_amdgcn_s_barrier();
}

// GEMM1: BM=128, BN=128, 512 thr (8 waves 2x4), MF=4, NF=2. K=768 (NT=12).
__global__ __launch_bounds__(512) void gemm_qkv_kernel(
    const short* __restrict__ A, const short* __restrict__ Bm,
    const float* __restrict__ bias, short* __restrict__ qkvh)
{
    constexpr int K = DIM, NT = 12;
    __shared__ short lsA0[8192], lsB0[8192], lsA1[8192], lsB1[8192];

    const int t    = threadIdx.x;
    const int lane = t & 63;
    const int wid  = t >> 6;
    const int wrow = wid >> 2, wcol = wid & 3;
    const int l16  = lane & 15;
    const int kg   = lane >> 4;
    const int row0 = blockIdx.y * 128;
    const int col0 = blockIdx.x * 128;

    const int srow = t >> 3;
    const int scol = ((t & 7) ^ (srow & 7)) * 8;
    const short* Ab = A  + (size_t)(row0 + srow) * K + scol;
    const short* Bb = Bm + (size_t)(col0 + srow) * K + scol;
    short* ldA0 = lsA0 + t * 8;  short* ldB0 = lsB0 + t * 8;
    short* ldA1 = lsA1 + t * 8;  short* ldB1 = lsB1 + t * 8;
    const int arow = wrow * 64 + l16;
    const int brow = wcol * 32 + l16;
    const int sw   = (l16 & 7) * 8;

    f32x4 acc[4][2];
#pragma unroll
    for (int i = 0; i < 4; ++i)
#pragma unroll
        for (int j = 0; j < 2; ++j) acc[i][j] = (f32x4){0.f, 0.f, 0.f, 0.f};

    stage_op<128>(Ab, K, 0, ldA0);
    stage_op<128>(Bb, K, 0, ldB0);
    stage_op<128>(Ab, K, 64, ldA1);
    stage_op<128>(Bb, K, 64, ldB1);
    waitvm<4>();
    __builtin_amdgcn_s_barrier();

#pragma unroll
    for (int kt = 0; kt < NT - 2; kt += 2) {
        phase_steady<4, 2, 128, 128, 4>(lsA0, lsB0, ldA0, ldB0, Ab, Bb, K,
                                        (kt + 2) * 64, arow, brow, kg, sw, acc);
        phase_steady<4, 2, 128, 128, 4>(lsA1, lsB1, ldA1, ldB1, Ab, Bb, K,
                                        (kt + 3) * 64, arow, brow, kg, sw, acc);
    }
    {
        bf16x8 af[2][4], bfr[2][2];
        read_frags<4, 2>(lsA0, lsB0, arow, brow, kg, sw, af, bfr);
        mfma_frags<4, 2>(af, bfr, acc);
        waitvm<0>();
        __builtin_amdgcn_s_barrier();
        read_frags<4, 2>(lsA1, lsB1, arow, brow, kg, sw, af, bfr);
        mfma_frags<4, 2>(af, bfr, acc);
    }

#pragma unroll
    for (int j = 0; j < 2; ++j) {
        const int col = col0 + wcol * 32 + j * 16 + l16;
        const int ty = col / DIM;
        const int hh = (col % DIM) >> 6;
        const int dd = col & 63;
        const float bv = bias[col];
        const size_t cbase = ((size_t)(ty * BB * NH) * SS) * HD;
#pragma unroll
        for (int i = 0; i < 4; ++i) {
            const int rbase = row0 + wrow * 64 + i * 16 + kg * 4;
#pragma unroll
            for (int r = 0; r < 4; ++r) {
                const int row = rbase + r;
                const int bq = row >> 11, sq = row & 2047;
                qkvh[cbase + (((size_t)(bq * NH + hh) * SS + sq) << 6) + dd] =
                    f2bf(acc[i][j][r] + bv);
            }
        }
    }
}

// GEMM2: BM=64, BN=128, 512 thr, MF=2, NF=2 (grid 6x64=384). NT=12. R8-exact.
__global__ __launch_bounds__(512) void gemm_out_kernel(
    const short* __restrict__ A, const short* __restrict__ Bm,
    const float* __restrict__ bias, float* __restrict__ C)
{
    constexpr int K = DIM, N = DIM, NT = 12;
    __shared__ short lsA0[4096], lsB0[8192], lsA1[4096], lsB1[8192];

    const int t    = threadIdx.x;
    const int lane = t & 63;
    const int wid  = t >> 6;
    const int wrow = wid >> 2, wcol = wid & 3;
    const int l16  = lane & 15;
    const int kg   = lane >> 4;
    const int row0 = blockIdx.y * 64;
    const int col0 = blockIdx.x * 128;

    const int srow = t >> 3;
    const int scol = ((t & 7) ^ (srow & 7)) * 8;
    const short* Ab = A  + (size_t)(row0 + srow) * K + scol;
    const short* Bb = Bm + (size_t)(col0 + srow) * K + scol;
    short* ldA0 = lsA0 + t * 8;  short* ldB0 = lsB0 + t * 8;
    short* ldA1 = lsA1 + t * 8;  short* ldB1 = lsB1 + t * 8;
    const int arow = wrow * 32 + l16;
    const int brow = wcol * 32 + l16;
    const int sw   = (l16 & 7) * 8;

    f32x4 acc[2][2];
#pragma unroll
    for (int i = 0; i < 2; ++i)
#pragma unroll
        for (int j = 0; j < 2; ++j) acc[i][j] = (f32x4){0.f, 0.f, 0.f, 0.f};

    stage_op<64>(Ab, K, 0, ldA0);
    stage_op<128>(Bb, K, 0, ldB0);
    stage_op<64>(Ab, K, 64, ldA1);
    stage_op<128>(Bb, K, 64, ldB1);
    waitvm<3>();
    __builtin_amdgcn_s_barrier();

#pragma unroll
    for (int kt = 0; kt < NT - 2; kt += 2) {
        phase_steady<2, 2, 64, 128, 3>(lsA0, lsB0, ldA0, ldB0, Ab, Bb, K,
                                       (kt + 2) * 64, arow, brow, kg, sw, acc);
        phase_steady<2, 2, 64, 128, 3>(lsA1, lsB1, ldA1, ldB1, Ab, Bb, K,
                                       (kt + 3) * 64, arow, brow, kg, sw, acc);
    }
    {
        bf16x8 af[2][2], bfr[2][2];
        read_frags<2, 2>(lsA0, lsB0, arow, brow, kg, sw, af, bfr);
        mfma_frags<2, 2>(af, bfr, acc);
        waitvm<0>();
        __builtin_amdgcn_s_barrier();
        read_frags<2, 2>(lsA1, lsB1, arow, brow, kg, sw, af, bfr);
        mfma_frags<2, 2>(af, bfr, acc);
    }

#pragma unroll
    for (int j = 0; j < 2; ++j) {
        const int col = col0 + wcol * 32 + j * 16 + l16;
        const float bv = bias[col];
#pragma unroll
        for (int i = 0; i < 2; ++i) {
            const int rbase = row0 + wrow * 32 + i * 16 + kg * 4;
#pragma unroll
            for (int r = 0; r < 4; ++r)
                C[(size_t)(rbase + r) * N + col] = acc[i][j][r] + bv;
        }
    }
}

// Sparse Fibonacci attention — R8 structure; R14: K-dot via v_dot2_f32_bf16
// (packed 2xbf16 dot + f32 acc). q and K stay packed: 4 dot2 per row replaces
// 8 cvt + 8 fma. V-pass / softmax unchanged.
__global__ __launch_bounds__(256) void fib_attn_kernel(
    const short* __restrict__ qkvh, short* __restrict__ attn)
{
    const int idx   = blockIdx.x;          // [0,1536)
    const int j     = idx >> 3;            // [0,192)
    const int bh    = (idx & 7) + 8 * (j >> 6);   // [0,24), pinned per XCD
    const int chunk = j & 63;              // [0,64)
    const int wid   = threadIdx.x >> 6;
    const int lane  = threadIdx.x & 63;
    const int ql    = lane >> 3;
    const int c     = lane & 7;
    const int s     = chunk * 32 + wid * 8 + ql;
    const int b = bh / NH, h = bh % NH;

    constexpr size_t TYB = (size_t)BB * NH * SS * HD;
    const size_t base = ((size_t)bh * SS) << 6;
    const short* Kp = qkvh + TYB + base;
    const short* Vp = qkvh + 2 * TYB + base;

    // q as 4 packed bf16-pair words (no conversion; feeds dot2 directly)
    const int4 qp = *(const int4*)(qkvh + base + ((size_t)s << 6) + c * 8);

    constexpr int NF = 17;
    const int fib[NF] = {0, 1, 2, 3, 5, 8, 13, 21, 34, 55, 89, 144,
                         233, 377, 610, 987, 1597};
    float sc[NF];
#pragma unroll
    for (int f = 0; f < NF; ++f) {
        const bool ok = (fib[f] <= s);
        const int sk = ok ? s - fib[f] : s;
        const int4 kv = *(const int4*)(Kp + ((size_t)sk << 6) + c * 8);
        float part = 0.f;
        asm("v_dot2_f32_bf16 %0, %1, %2, %0" : "+v"(part) : "v"(kv.x), "v"(qp.x));
        asm("v_dot2_f32_bf16 %0, %1, %2, %0" : "+v"(part) : "v"(kv.y), "v"(qp.y));
        asm("v_dot2_f32_bf16 %0, %1, %2, %0" : "+v"(part) : "v"(kv.z), "v"(qp.z));
        asm("v_dot2_f32_bf16 %0, %1, %2, %0" : "+v"(part) : "v"(kv.w), "v"(qp.w));
        part += __shfl_xor(part, 1, 64);
        part += __shfl_xor(part, 2, 64);
        part += __shfl_xor(part, 4, 64);
        sc[f] = ok ? part * 0.125f : -1e30f;
    }

    float mx = sc[0];
#pragma unroll
    for (int f = 1; f < NF; ++f) mx = fmaxf(mx, sc[f]);
    float den = 0.f;
#pragma unroll
    for (int f = 0; f < NF; ++f) { sc[f] = __expf(sc[f] - mx); den += sc[f]; }

    float o[8];
#pragma unroll
    for (int e = 0; e < 8; ++e) o[e] = 0.f;
#pragma unroll
    for (int f = 0; f < NF; ++f) {
        const int sk = (fib[f] <= s) ? s - fib[f] : s;
        bf16x8 vv = *(const bf16x8*)(Vp + ((size_t)sk << 6) + c * 8);
        const float w = sc[f];
#pragma unroll
        for (int e = 0; e < 8; ++e) o[e] += w * bf2f(vv[e]);
    }

    const float inv = 1.f / den;
    short8 r;
#pragma unroll
    for (int e = 0; e < 8; ++e) r[e] = f2bf(o[e] * inv);
    *(short8*)(attn + (size_t)(b * SS + s) * DIM + h * HD + c * 8) = r;
}

extern "C" void kernel_launch(void* const* d_in, const int* in_sizes, int n_in,
                              void* d_out, int out_size, void* d_ws, size_t ws_size,
                              hipStream_t stream)
{
    const float* x     = (const float*)d_in[0];
    const float* w_qkv = (const float*)d_in[1];
    const float* b_qkv = (const float*)d_in[2];
    const float* w_out = (const float*)d_in[3];
    const float* b_out = (const float*)d_in[4];
    float* out = (float*)d_out;

    short* qkvh  = (short*)d_ws;                              // [3][2][12][2048][64] bf16
    short* attnb = (short*)((char*)d_ws + 18874368);          // [4096][768] bf16
    short* xb    = (short*)((char*)d_ws + 25165824);          // [4096][768] bf16
    short* wqkvb = (short*)((char*)d_ws + 31457280);          // [2304][768] bf16
    short* woutb = (short*)((char*)d_ws + 34996224);          // [768][768]  bf16

    conv_kernel<<<dim3(2688, 1, 1), dim3(256, 1, 1), 0, stream>>>(
        x, xb, w_qkv, wqkvb, w_out, woutb);

    gemm_qkv_kernel<<<dim3(QKVN / 128, MM / 128, 1), dim3(512, 1, 1), 0, stream>>>(
        xb, wqkvb, b_qkv, qkvh);

    fib_attn_kernel<<<dim3(1536, 1, 1), dim3(256, 1, 1), 0, stream>>>(qkvh, attnb);

    gemm_out_kernel<<<dim3(DIM / 128, MM / 64, 1), dim3(512, 1, 1), 0, stream>>>(
        attnb, woutb, b_out, out);
}